// Round 13
// baseline (148.481 us; speedup 1.0000x reference)
//
#include <hip/hip_runtime.h>
#include <math.h>

#define BB 8
#define CH 128
#define HH 152
#define WWID 272
#define HWSZ (HH*WWID)
#define NDET 128
#define NHEAD 8
#define HDIM 16
#define DFF 512
#define NDB (BB*NDET)      // 1024 dets
#define KSTRIDE 1152       // 9*CH floats of pooled k per det
#define CHUNK 16           // rows per LDS slab: 16*276*4 = 17664B -> 8 blocks/CU
#define RHALF 76           // rows per half-plane block (152 = 2*76; chunks 16,16,16,16,12)
#define SROW 276           // S row stride in floats (273 used, %4==0)

typedef float f4v __attribute__((ext_vector_type(4)));

__device__ __forceinline__ float dot4(float4 w, float4 u, float s) {
    s = fmaf(w.x, u.x, s);
    s = fmaf(w.y, u.y, s);
    s = fmaf(w.z, u.z, s);
    s = fmaf(w.w, u.w, s);
    return s;
}

// GFX9/CDNA DPP wavefront inclusive scan: VALU-only (no ds_bpermute).
// row_shr:1/2/4/8 within 16-lane rows, then row_bcast15 (rows 1,3) and
// row_bcast31 (rows 2,3). old=0 + bound_ctrl=false -> masked/invalid add 0.
// DPP ctrl/masks must be ICEs -> template parameters.
template<int CTRL, int RMASK>
__device__ __forceinline__ float dpp_add_step(float x) {
    int y = __builtin_amdgcn_update_dpp(0, __builtin_bit_cast(int, x),
                                        CTRL, RMASK, 0xf, false);
    return x + __builtin_bit_cast(float, y);
}
__device__ __forceinline__ float wave_incl_scan(float x) {
    x = dpp_add_step<0x111, 0xf>(x);   // row_shr:1
    x = dpp_add_step<0x112, 0xf>(x);   // row_shr:2
    x = dpp_add_step<0x114, 0xf>(x);   // row_shr:4
    x = dpp_add_step<0x118, 0xf>(x);   // row_shr:8
    x = dpp_add_step<0x142, 0xa>(x);   // row_bcast:15 -> rows 1,3
    x = dpp_add_step<0x143, 0xc>(x);   // row_bcast:31 -> rows 2,3
    return x;
}

// ============================================================================
// K1: fused copy + pooling partials. One block per (plane, row-half):
// 2048 blocks. Waves stream rows (read -> NT store = the copy) and build an
// exclusive prefix-sum per row in LDS (DPP scan, VALU-only); det-threads
// accumulate PARTIAL box cell sums -> kpart[rhalf]. Tail combines + divides.
// ============================================================================
__global__ __launch_bounds__(256) void pool_stream(
    const float* __restrict__ x, const int* __restrict__ dets,
    float* __restrict__ kpart, float* __restrict__ out)
{
    const int bid   = blockIdx.x;          // plane*2 + rhalf
    const int t     = threadIdx.x;
    const int plane = bid >> 1, rhalf = bid & 1;
    const int b     = plane >> 7, ch = plane & 127;
    const int lane  = t & 63,  w  = t >> 6;
    const int rbeg  = rhalf * RHALF;

    __shared__ float S[CHUNK * SROW];      // prefix sums; reused as scratch

    const float* xp = x + ((size_t)b * CH + ch) * HWSZ;
    f4v* o4 = (f4v*)(out + ((size_t)b * CH + ch) * HWSZ);

    // ---- det-thread setup: thread d & d+128 both own det d ----
    const int d = t & 127, half = t >> 7;
    const int4 dv = *((const int4*)(dets + (size_t)(b * NDET + d) * 4));
    const int sx = dv.x, sy = dv.y, ex = dv.z, ey = dv.w;
    const int Lx = ex - sx, Ly = ey - sy;
    // cell edges (cells OVERLAP due to floor/ceil in reference)
    const int xs1 = sx + Lx / 3,        xs2 = sx + 2 * Lx / 3;
    const int xe0 = sx + (Lx + 2) / 3,  xe1 = sx + (2 * Lx + 2) / 3;
    const int ys1 = sy + Ly / 3,        ys2 = sy + 2 * Ly / 3;
    const int ye0 = sy + (Ly + 2) / 3,  ye1 = sy + (2 * Ly + 2) / 3;

    float acc[9] = {0.f,0.f,0.f,0.f,0.f,0.f,0.f,0.f,0.f};

    #pragma unroll 1
    for (int cbeg = rbeg; cbeg < rbeg + RHALF; cbeg += CHUNK) {
        const int csize = (rbeg + RHALF - cbeg < CHUNK) ? (rbeg + RHALF - cbeg) : CHUNK;

        // ---- phase A: stream + scan rows (wave-parallel, prefetched) ----
        {
            int rl = w;                       // wave w does rows w, w+4, ...
            f4v vm = (f4v)(0.f), ve = (f4v)(0.f);
            bool have = (rl < csize);
            if (have) {
                const f4v* rowp = (const f4v*)(xp + (size_t)(cbeg + rl) * WWID);
                vm = rowp[lane];
                if (lane < 4) ve = rowp[64 + lane];
            }
            while (have) {
                const int rc = rl;
                f4v v = vm, e = ve;
                rl += 4;
                have = (rl < csize);
                if (have) {                   // prefetch next row
                    const f4v* rowp = (const f4v*)(xp + (size_t)(cbeg + rl) * WWID);
                    vm = rowp[lane];
                    if (lane < 4) ve = rowp[64 + lane];
                }
                // copy current row to out (NT: don't evict x from L3)
                __builtin_nontemporal_store(v, &o4[(size_t)(cbeg + rc) * 68 + lane]);
                if (lane < 4)
                    __builtin_nontemporal_store(e, &o4[(size_t)(cbeg + rc) * 68 + 64 + lane]);
                // exclusive prefix: S[c] = sum of cols [0, c)
                float T = v[0] + v[1] + v[2] + v[3];
                float s = wave_incl_scan(T);            // DPP, VALU-only
                float off0 = s - T;
                float* Sr = S + rc * SROW;
                f4v sm;
                sm[0] = off0;
                sm[1] = off0 + v[0];
                sm[2] = off0 + v[0] + v[1];
                sm[3] = off0 + v[0] + v[1] + v[2];
                *(f4v*)&Sr[4 * lane] = sm;
                // extension cols 256..271 live in lanes 0..3 (e)
                float Te = (lane < 4) ? (e[0]+e[1]+e[2]+e[3]) : 0.f;
                float Tei = Te;                          // 4-lane inclusive scan
                Tei = dpp_add_step<0x111, 0xf>(Tei);     // row_shr:1
                Tei = dpp_add_step<0x112, 0xf>(Tei);     // row_shr:2
                float R    = __shfl(s, 63);              // total of cols 0..255
                float Esum = __shfl(Tei, 3);             // total of cols 256..271
                if (lane < 4) {
                    float offE = R + (Tei - Te);
                    f4v se;
                    se[0] = offE;
                    se[1] = offE + e[0];
                    se[2] = offE + e[0] + e[1];
                    se[3] = offE + e[0] + e[1] + e[2];
                    *(f4v*)&Sr[256 + 4 * lane] = se;
                }
                if (lane == 0) Sr[272] = R + Esum;
            }
        }
        __syncthreads();

        // ---- phase B: det partial accumulation from prefix sums ----
        {
            int lo = (sy > cbeg) ? sy : cbeg;
            int hi = (ey < cbeg + csize) ? ey : (cbeg + csize);
            if (lo < hi) {
                int mid = (lo + hi + 1) >> 1;
                int y0 = half ? mid : lo;
                int y1 = half ? hi  : mid;
                for (int y = y0; y < y1; ++y) {
                    const float* Sr = S + (y - cbeg) * SROW;
                    float c0 = Sr[xe0] - Sr[sx];
                    float c1 = Sr[xe1] - Sr[xs1];
                    float c2 = Sr[ex]  - Sr[xs2];
                    float m0 = (y < ye0) ? 1.f : 0.f;
                    float m1 = (y >= ys1 && y < ye1) ? 1.f : 0.f;
                    float m2 = (y >= ys2) ? 1.f : 0.f;
                    acc[0] = fmaf(m0, c0, acc[0]); acc[1] = fmaf(m0, c1, acc[1]); acc[2] = fmaf(m0, c2, acc[2]);
                    acc[3] = fmaf(m1, c0, acc[3]); acc[4] = fmaf(m1, c1, acc[4]); acc[5] = fmaf(m1, c2, acc[5]);
                    acc[6] = fmaf(m2, c0, acc[6]); acc[7] = fmaf(m2, c1, acc[7]); acc[8] = fmaf(m2, c2, acc[8]);
                }
            }
        }
        __syncthreads();
    }

    // ---- combine thread-halves via S (reused as scratch), write partials ----
    if (half) {
        #pragma unroll
        for (int j = 0; j < 9; ++j) S[d * 9 + j] = acc[j];
    }
    __syncthreads();
    if (!half) {
        float* kd = kpart + ((size_t)rhalf * NDB + (size_t)(b * NDET + d)) * KSTRIDE + ch;
        #pragma unroll
        for (int j = 0; j < 9; ++j)
            kd[j * CH] = acc[j] + S[d * 9 + j];    // NO area divide (tail does it)
    }
}

// ============================================================================
// K2: fully-fused transformer tail. 512 blocks x 2 dets x 256 threads.
// k-combine -> QKV -> attention -> Wo+LN1 -> FFN1 -> FFN2+LN2 -> scatter.
// ============================================================================
__global__ __launch_bounds__(256) void tail_kernel(
    const float* __restrict__ x, const float* __restrict__ vis,
    const int* __restrict__ dets, const int* __restrict__ inds,
    const float* __restrict__ kpA, const float* __restrict__ kpB,
    const float* __restrict__ Wqkv, const float* __restrict__ bqkv,
    const float* __restrict__ Wo,   const float* __restrict__ bo,
    const float* __restrict__ W1,   const float* __restrict__ b1,
    const float* __restrict__ W2,   const float* __restrict__ b2,
    const float* __restrict__ g2,   const float* __restrict__ be2,
    const float* __restrict__ g3,   const float* __restrict__ be3,
    float* __restrict__ out)
{
    const int bid = blockIdx.x;
    const int t   = threadIdx.x;
    const int d0  = bid * 2;           // 2 dets per block, never straddles images
    const int b   = d0 >> 7;
    const int o   = t & 127, dl = t >> 7;

    __shared__ float kbuf[2 * 9 * CH];   // pooled k (area-divided)
    __shared__ float kp[2 * 9 * CH];
    __shared__ float vp[2 * 9 * CH];
    __shared__ float invA[2][9];
    __shared__ float qv[2][CH];
    __shared__ float qp[2][CH];
    __shared__ float attl[2][NHEAD][9];
    __shared__ float aov[2][CH];
    __shared__ float Tv[2][CH];
    __shared__ float h1[2][DFF];
    __shared__ float part2[2][2][CH];    // [half][det][o]
    __shared__ float wst[4][2];

    // ---- inverse cell areas (18 threads) ----
    if (t < 18) {
        int dd = t / 9, slot = t - dd * 9;
        const int4 dv = *((const int4*)(dets + (size_t)(b * NDET + ((d0 + dd) & 127)) * 4));
        int sx = dv.x, sy = dv.y, ex = dv.z, ey = dv.w;
        int Lx = ex - sx, Ly = ey - sy;
        int xs1 = sx + Lx / 3,       xs2 = sx + 2 * Lx / 3;
        int xe0 = sx + (Lx + 2) / 3, xe1 = sx + (2 * Lx + 2) / 3;
        int ys1 = sy + Ly / 3,       ys2 = sy + 2 * Ly / 3;
        int ye0 = sy + (Ly + 2) / 3, ye1 = sy + (2 * Ly + 2) / 3;
        int xi = slot % 3, yi = slot / 3;
        int wdt = (xi == 0) ? (xe0 - sx) : (xi == 1) ? (xe1 - xs1) : (ex - xs2);
        int hgt = (yi == 0) ? (ye0 - sy) : (yi == 1) ? (ye1 - ys1) : (ey - ys2);
        invA[dd][slot] = 1.0f / (float)(hgt * wdt);
    }
    // ---- q gather + positional embedding ----
    {
        int p = inds[b * NDET + ((d0 + dl) & 127)];
        float qval = x[((size_t)b * CH + o) * HWSZ + p];
        float vv   = vis[(size_t)b * HWSZ + p];
        int vidx   = (int)(vv * 10.0f);
        float fr   = powf(10000.0f, -(float)(o & 126) * (1.0f / 128.0f));
        float ang  = 0.1f * (float)vidx * fr;
        qv[dl][o]  = qval + ((o & 1) ? cosf(ang) : sinf(ang));
    }
    __syncthreads();

    // ---- combine pooling partials + area divide ----
    for (int i = t; i < 2 * KSTRIDE; i += 256) {
        int dd = (i >= KSTRIDE);
        int r  = i - dd * KSTRIDE;
        int slot = r >> 7;
        float vA = kpA[(size_t)(d0 + dd) * KSTRIDE + r];
        float vB = kpB[(size_t)(d0 + dd) * KSTRIDE + r];
        kbuf[dd * KSTRIDE + r] = (vA + vB) * invA[dd][slot];
    }
    __syncthreads();

    // ---- qp = Wq @ qv ----
    {
        const float4* wr = (const float4*)(Wqkv + (size_t)o * CH);
        const float4* qq = (const float4*)&qv[dl][0];
        float s = 0.f;
        #pragma unroll 8
        for (int i = 0; i < 32; ++i) s = dot4(wr[i], qq[i], s);
        qp[dl][o] = s + bqkv[o];
    }
    // ---- kp/vp: 18 rows x 128 outs, which = k or v ----
    {
        const int which = t >> 7;
        const float4* wr = (const float4*)(Wqkv + (size_t)(CH + which * CH + o) * CH);
        float acc[18];
        #pragma unroll
        for (int r = 0; r < 18; ++r) acc[r] = 0.f;
        for (int i = 0; i < 32; ++i) {
            float4 w = wr[i];
            #pragma unroll
            for (int r = 0; r < 18; ++r) {
                float4 a = ((const float4*)kbuf)[r * 32 + i];
                acc[r] = dot4(w, a, acc[r]);
            }
        }
        const float bias = bqkv[CH + which * CH + o];
        float* dst = which ? vp : kp;
        #pragma unroll
        for (int r = 0; r < 18; ++r) dst[r * CH + o] = acc[r] + bias;
    }
    __syncthreads();

    // ---- attention scores ----
    if (o < 72) {
        int h = o / 9, s = o - h * 9;
        const float* qh = &qp[dl][h * HDIM];
        const float* kh = &kp[dl * KSTRIDE + s * CH + h * HDIM];
        float a = 0.f;
        #pragma unroll
        for (int e = 0; e < HDIM; ++e) a = fmaf(qh[e], kh[e], a);
        attl[dl][h][s] = a * 0.25f;
    }
    __syncthreads();
    // ---- softmax per (det, head) ----
    if (o < 8) {
        float m = attl[dl][o][0];
        #pragma unroll
        for (int s = 1; s < 9; ++s) m = fmaxf(m, attl[dl][o][s]);
        float e[9]; float sum = 0.f;
        #pragma unroll
        for (int s = 0; s < 9; ++s) { e[s] = expf(attl[dl][o][s] - m); sum += e[s]; }
        float inv = 1.0f / sum;
        #pragma unroll
        for (int s = 0; s < 9; ++s) attl[dl][o][s] = e[s] * inv;
    }
    __syncthreads();
    // ---- ao = att @ vp ----
    {
        int h = o >> 4;
        float a = 0.f;
        #pragma unroll
        for (int s = 0; s < 9; ++s) a = fmaf(attl[dl][h][s], vp[dl * KSTRIDE + s * CH + o], a);
        aov[dl][o] = a;
    }
    __syncthreads();

    // ---- Wo + resid ----
    float v1;
    {
        const float4* wr = (const float4*)(Wo + (size_t)o * CH);
        const float4* u4 = (const float4*)&aov[dl][0];
        float s = 0.f;
        #pragma unroll 8
        for (int i = 0; i < 32; ++i) s = dot4(wr[i], u4[i], s);
        v1 = qv[dl][o] + s + bo[o];
    }
    // ---- LN1 (det dl spans waves 2dl, 2dl+1) ----
    {
        float s1 = v1, s2 = v1 * v1;
        #pragma unroll
        for (int off = 32; off >= 1; off >>= 1) {
            s1 += __shfl_xor(s1, off);
            s2 += __shfl_xor(s2, off);
        }
        if ((t & 63) == 0) { wst[t >> 6][0] = s1; wst[t >> 6][1] = s2; }
    }
    __syncthreads();
    {
        float sum = wst[2 * dl][0] + wst[2 * dl + 1][0];
        float sq  = wst[2 * dl][1] + wst[2 * dl + 1][1];
        float m   = sum * (1.0f / 128.0f);
        float var = sq  * (1.0f / 128.0f) - m * m;
        Tv[dl][o] = (v1 - m) * rsqrtf(var + 1e-5f) * g2[o] + be2[o];
    }
    __syncthreads();

    // ---- FFN1: 512 outs x 2 dets ----
    #pragma unroll
    for (int rep = 0; rep < 2; ++rep) {
        int oo = t + rep * 256;
        const float4* wr = (const float4*)(W1 + (size_t)oo * CH);
        float a0 = 0.f, a1 = 0.f;
        for (int i = 0; i < 32; ++i) {
            float4 w = wr[i];
            a0 = dot4(w, ((const float4*)&Tv[0][0])[i], a0);
            a1 = dot4(w, ((const float4*)&Tv[1][0])[i], a1);
        }
        float bb = b1[oo];
        h1[0][oo] = fmaxf(a0 + bb, 0.f);
        h1[1][oo] = fmaxf(a1 + bb, 0.f);
    }
    __syncthreads();

    // ---- FFN2 partials: thread (o, hf) does half the 512-dot for both dets ----
    {
        const int hf = t >> 7;
        const float4* wr = (const float4*)(W2 + (size_t)o * DFF + hf * (DFF / 2));
        float a0 = 0.f, a1 = 0.f;
        #pragma unroll 4
        for (int i = 0; i < 64; ++i) {
            float4 w = wr[i];
            a0 = dot4(w, ((const float4*)&h1[0][hf * 256])[i], a0);
            a1 = dot4(w, ((const float4*)&h1[1][hf * 256])[i], a1);
        }
        part2[hf][0][o] = a0;
        part2[hf][1][o] = a1;
    }
    __syncthreads();
    float v2 = part2[0][dl][o] + part2[1][dl][o] + b2[o] + Tv[dl][o];
    // ---- LN2 ----
    {
        float s1 = v2, s2 = v2 * v2;
        #pragma unroll
        for (int off = 32; off >= 1; off >>= 1) {
            s1 += __shfl_xor(s1, off);
            s2 += __shfl_xor(s2, off);
        }
        if ((t & 63) == 0) { wst[t >> 6][0] = s1; wst[t >> 6][1] = s2; }
    }
    __syncthreads();
    {
        float sum = wst[2 * dl][0] + wst[2 * dl + 1][0];
        float sq  = wst[2 * dl][1] + wst[2 * dl + 1][1];
        float m   = sum * (1.0f / 128.0f);
        float var = sq  * (1.0f / 128.0f) - m * m;
        float ov  = (v2 - m) * rsqrtf(var + 1e-5f) * g3[o] + be3[o];
        int p = inds[b * NDET + ((d0 + dl) & 127)];
        out[((size_t)b * CH + o) * HWSZ + p] = ov;       // scattered final write
    }
}

// ============================================================================
// Fallback path (ws too small): copy, then fully-fused det kernel
// ============================================================================
__global__ __launch_bounds__(256) void copy_x(const f4v* __restrict__ src,
                                              f4v* __restrict__ dst, size_t n4) {
    size_t i = (size_t)blockIdx.x * 256 + threadIdx.x;
    const size_t stride = (size_t)gridDim.x * 256;
    for (; i < n4; i += stride) {
        f4v v = src[i];
        __builtin_nontemporal_store(v, &dst[i]);
    }
}

__device__ __forceinline__ float block_layernorm(float v, int t,
        const float* __restrict__ gamma, const float* __restrict__ beta,
        float* redA, float* redB) {
    float s1 = v, s2 = v * v;
    #pragma unroll
    for (int off = 32; off >= 1; off >>= 1) {
        s1 += __shfl_xor(s1, off);
        s2 += __shfl_xor(s2, off);
    }
    if ((t & 63) == 0) { redA[t >> 6] = s1; redB[t >> 6] = s2; }
    __syncthreads();
    float sum = redA[0] + redA[1] + redA[2] + redA[3];
    float sq  = redB[0] + redB[1] + redB[2] + redB[3];
    __syncthreads();
    float m   = sum * (1.0f / 128.0f);
    float var = sq  * (1.0f / 128.0f) - m * m;
    float r = 0.f;
    if (t < CH) r = (v - m) * rsqrtf(var + 1e-5f) * gamma[t] + beta[t];
    return r;
}

__global__ __launch_bounds__(256) void er_fused_fb(
    const float* __restrict__ x, const float* __restrict__ vis,
    const int* __restrict__ dets, const int* __restrict__ inds,
    const float* __restrict__ Wqkv, const float* __restrict__ bqkv,
    const float* __restrict__ Wo,   const float* __restrict__ bo,
    const float* __restrict__ W1,   const float* __restrict__ b1,
    const float* __restrict__ W2,   const float* __restrict__ b2,
    const float* __restrict__ g2,   const float* __restrict__ be2,
    const float* __restrict__ g3,   const float* __restrict__ be3,
    float* __restrict__ out)
{
    const int bid = blockIdx.x;
    const int t   = threadIdx.x;

    __shared__ float kbuf[9][CH];
    __shared__ float qv[CH];
    __shared__ float qp[CH];
    __shared__ float kp[9][CH];
    __shared__ float vp[9][CH];
    __shared__ float att[NHEAD][9];
    __shared__ float aov[CH];
    __shared__ float tv[CH];
    __shared__ float h1[DFF];
    __shared__ float part[256];
    __shared__ float redA[4], redB[4];
    __shared__ float msk[48][4];

    const int b = bid >> 7;
    const int n = bid & (NDET - 1);

    const int4 dv = *((const int4*)(dets + (size_t)(b * NDET + n) * 4));
    const int sx = dv.x, sy = dv.y, ex = dv.z, ey = dv.w;
    const int Lx = ex - sx, Ly = ey - sy;
    const int xs1 = sx + Lx / 3,        xs2 = sx + 2 * Lx / 3;
    const int xe0 = sx + (Lx + 2) / 3,  xe1 = sx + (2 * Lx + 2) / 3;
    const int ys1 = sy + Ly / 3,        ys2 = sy + 2 * Ly / 3;
    const int ye0 = sy + (Ly + 2) / 3,  ye1 = sy + (2 * Ly + 2) / 3;

    const int p = inds[b * NDET + n];

    if (t < 48) {
        int y = sy + t;
        bool inb = (y < ey);
        msk[t][0] = (inb && y < ye0)              ? 1.f : 0.f;
        msk[t][1] = (inb && y >= ys1 && y < ye1)  ? 1.f : 0.f;
        msk[t][2] = (inb && y >= ys2)             ? 1.f : 0.f;
        msk[t][3] = 0.f;
    }
    if (t < CH) {
        float qval = x[((size_t)b * CH + t) * HWSZ + p];
        float vv   = vis[(size_t)b * HWSZ + p];
        int vidx   = (int)(vv * 10.0f);
        float fr   = powf(10000.0f, -(float)(t & 126) * (1.0f / 128.0f));
        float ang  = 0.1f * (float)vidx * fr;
        float pe   = (t & 1) ? cosf(ang) : sinf(ang);
        qv[t] = qval + pe;
    }
    __syncthreads();

    {
        const int g   = t >> 4;
        const int lx  = t & 15;
        const int sx4 = sx & ~3;
        const int xb  = sx4 + lx * 4;
        const int lxmax = ((ex - 1) - sx4) >> 2;
        const int xba = sx4 + ((lx < lxmax) ? lx : lxmax) * 4;

        float4 mx0, mx1, mx2;
        {
            float m0[4], m1[4], m2[4];
            #pragma unroll
            for (int e = 0; e < 4; ++e) {
                int xx = xb + e;
                m0[e] = (xx >= sx  && xx < xe0) ? 1.f : 0.f;
                m1[e] = (xx >= xs1 && xx < xe1) ? 1.f : 0.f;
                m2[e] = (xx >= xs2 && xx < ex ) ? 1.f : 0.f;
            }
            mx0 = make_float4(m0[0], m0[1], m0[2], m0[3]);
            mx1 = make_float4(m1[0], m1[1], m1[2], m1[3]);
            mx2 = make_float4(m2[0], m2[1], m2[2], m2[3]);
        }

        const int rows_n = ey - sy;
        const int nch    = (rows_n + 7) >> 3;

        for (int c = 0; c < 8; ++c) {
            const int dd = g + c * 16;
            const float* base = x + ((size_t)b * CH + dd) * HWSZ + xba;
            float4 ac0 = make_float4(0.f,0.f,0.f,0.f);
            float4 ac1 = make_float4(0.f,0.f,0.f,0.f);
            float4 ac2 = make_float4(0.f,0.f,0.f,0.f);
            for (int ck = 0; ck < nch; ++ck) {
                const int y0 = sy + (ck << 3);
                float4 v[8];
                #pragma unroll
                for (int k = 0; k < 8; ++k) {
                    int y = y0 + k;
                    y = (y < ey) ? y : (ey - 1);
                    v[k] = *(const float4*)(base + (size_t)y * WWID);
                }
                #pragma unroll
                for (int k = 0; k < 8; ++k) {
                    const float4 m = *(const float4*)&msk[(y0 - sy) + k][0];
                    ac0.x = fmaf(m.x, v[k].x, ac0.x); ac0.y = fmaf(m.x, v[k].y, ac0.y);
                    ac0.z = fmaf(m.x, v[k].z, ac0.z); ac0.w = fmaf(m.x, v[k].w, ac0.w);
                    ac1.x = fmaf(m.y, v[k].x, ac1.x); ac1.y = fmaf(m.y, v[k].y, ac1.y);
                    ac1.z = fmaf(m.y, v[k].z, ac1.z); ac1.w = fmaf(m.y, v[k].w, ac1.w);
                    ac2.x = fmaf(m.z, v[k].x, ac2.x); ac2.y = fmaf(m.z, v[k].y, ac2.y);
                    ac2.z = fmaf(m.z, v[k].z, ac2.z); ac2.w = fmaf(m.z, v[k].w, ac2.w);
                }
            }
            float a[9];
            a[0] = dot4(mx0, ac0, 0.f); a[1] = dot4(mx1, ac0, 0.f); a[2] = dot4(mx2, ac0, 0.f);
            a[3] = dot4(mx0, ac1, 0.f); a[4] = dot4(mx1, ac1, 0.f); a[5] = dot4(mx2, ac1, 0.f);
            a[6] = dot4(mx0, ac2, 0.f); a[7] = dot4(mx1, ac2, 0.f); a[8] = dot4(mx2, ac2, 0.f);
            #pragma unroll
            for (int jj = 0; jj < 9; ++jj) {
                a[jj] += __shfl_xor(a[jj], 8);
                a[jj] += __shfl_xor(a[jj], 4);
                a[jj] += __shfl_xor(a[jj], 2);
                a[jj] += __shfl_xor(a[jj], 1);
            }
            if (lx == 0) {
                int w0 = xe0 - sx, w1 = xe1 - xs1, w2 = ex - xs2;
                int h0 = ye0 - sy, h1r = ye1 - ys1, h2 = ey - ys2;
                kbuf[0][dd] = a[0] / (float)(h0 * w0);
                kbuf[1][dd] = a[1] / (float)(h0 * w1);
                kbuf[2][dd] = a[2] / (float)(h0 * w2);
                kbuf[3][dd] = a[3] / (float)(h1r * w0);
                kbuf[4][dd] = a[4] / (float)(h1r * w1);
                kbuf[5][dd] = a[5] / (float)(h1r * w2);
                kbuf[6][dd] = a[6] / (float)(h2 * w0);
                kbuf[7][dd] = a[7] / (float)(h2 * w1);
                kbuf[8][dd] = a[8] / (float)(h2 * w2);
            }
        }
    }
    __syncthreads();

    if (t < CH) {
        const float4* wr = (const float4*)(Wqkv + (size_t)t * CH);
        const float4* qq = (const float4*)qv;
        float s = 0.f;
        #pragma unroll 8
        for (int i = 0; i < CH / 4; ++i) s = dot4(wr[i], qq[i], s);
        qp[t] = s + bqkv[t];
    }
    {
        const int o = t & (CH - 1);
        const int which = t >> 7;
        const float4* wr = (const float4*)(Wqkv + (size_t)(CH + which * CH + o) * CH);
        float acc[9] = {0.f,0.f,0.f,0.f,0.f,0.f,0.f,0.f,0.f};
        #pragma unroll 4
        for (int i = 0; i < CH / 4; ++i) {
            float4 w = wr[i];
            #pragma unroll
            for (int s = 0; s < 9; ++s) {
                float4 kk = ((const float4*)(&kbuf[s][0]))[i];
                acc[s] = dot4(w, kk, acc[s]);
            }
        }
        float bias = bqkv[CH + which * CH + o];
        if (which == 0) {
            #pragma unroll
            for (int s = 0; s < 9; ++s) kp[s][o] = acc[s] + bias;
        } else {
            #pragma unroll
            for (int s = 0; s < 9; ++s) vp[s][o] = acc[s] + bias;
        }
    }
    __syncthreads();

    if (t < NHEAD * 9) {
        int h = t / 9, s = t - h * 9;
        const float* qh = qp + h * HDIM;
        const float* kh = &kp[s][h * HDIM];
        float a = 0.f;
        #pragma unroll
        for (int e = 0; e < HDIM; ++e) a = fmaf(qh[e], kh[e], a);
        att[h][s] = a * 0.25f;
    }
    __syncthreads();

    if (t < NHEAD) {
        float m = att[t][0];
        #pragma unroll
        for (int s = 1; s < 9; ++s) m = fmaxf(m, att[t][s]);
        float e[9]; float sum = 0.f;
        #pragma unroll
        for (int s = 0; s < 9; ++s) { e[s] = expf(att[t][s] - m); sum += e[s]; }
        float inv = 1.0f / sum;
        #pragma unroll
        for (int s = 0; s < 9; ++s) att[t][s] = e[s] * inv;
    }
    __syncthreads();

    if (t < CH) {
        int h = t >> 4;
        float a = 0.f;
        #pragma unroll
        for (int s = 0; s < 9; ++s) a = fmaf(att[h][s], vp[s][t], a);
        aov[t] = a;
    }
    __syncthreads();

    float v1 = 0.f;
    if (t < CH) {
        const float4* wr = (const float4*)(Wo + (size_t)t * CH);
        const float4* u4 = (const float4*)aov;
        float s = 0.f;
        #pragma unroll 8
        for (int i = 0; i < CH / 4; ++i) s = dot4(wr[i], u4[i], s);
        v1 = qv[t] + s + bo[t];
    }
    float t1 = block_layernorm(v1, t, g2, be2, redA, redB);
    if (t < CH) tv[t] = t1;
    __syncthreads();

    #pragma unroll
    for (int rep = 0; rep < 2; ++rep) {
        int o = t + rep * 256;
        const float4* wr = (const float4*)(W1 + (size_t)o * CH);
        const float4* u4 = (const float4*)tv;
        float s = 0.f;
        #pragma unroll 8
        for (int i = 0; i < CH / 4; ++i) s = dot4(wr[i], u4[i], s);
        h1[o] = fmaxf(s + b1[o], 0.f);
    }
    __syncthreads();

    {
        int o = t & (CH - 1), hf = t >> 7;
        const float4* wr = (const float4*)(W2 + (size_t)o * DFF + hf * (DFF / 2));
        const float4* u4 = (const float4*)(h1 + hf * (DFF / 2));
        float s = 0.f;
        #pragma unroll 8
        for (int i = 0; i < DFF / 8; ++i) s = dot4(wr[i], u4[i], s);
        part[t] = s;
    }
    __syncthreads();

    float v2 = 0.f;
    if (t < CH) {
        float t2 = part[t] + part[t + 128] + b2[t];
        v2 = tv[t] + t2;
    }
    float outv = block_layernorm(v2, t, g3, be3, redA, redB);
    if (t < CH) out[((size_t)b * CH + t) * HWSZ + p] = outv;
}

extern "C" void kernel_launch(void* const* d_in, const int* in_sizes, int n_in,
                              void* d_out, int out_size, void* d_ws, size_t ws_size,
                              hipStream_t stream) {
    const float* x    = (const float*)d_in[0];
    const float* vis  = (const float*)d_in[1];
    const int*   dets = (const int*)d_in[2];
    const int*   inds = (const int*)d_in[3];
    const float* Wqkv = (const float*)d_in[4];
    const float* bqkv = (const float*)d_in[5];
    const float* Wo   = (const float*)d_in[6];
    const float* bo   = (const float*)d_in[7];
    const float* W1   = (const float*)d_in[8];
    const float* b1   = (const float*)d_in[9];
    const float* W2   = (const float*)d_in[10];
    const float* b2   = (const float*)d_in[11];
    const float* g2   = (const float*)d_in[12];
    const float* be2  = (const float*)d_in[13];
    const float* g3   = (const float*)d_in[14];
    const float* be3  = (const float*)d_in[15];
    float* out = (float*)d_out;

    const size_t SZ_KP = (size_t)NDB * KSTRIDE;          // one partial buffer
    const size_t need  = 2 * SZ_KP * sizeof(float);

    const size_t N4 = (size_t)BB * CH * HWSZ / 4;
    if (ws_size >= need) {
        float* kpA = (float*)d_ws;
        float* kpB = kpA + SZ_KP;

        pool_stream<<<dim3(2048), dim3(256), 0, stream>>>(x, dets, kpA, out);
        tail_kernel<<<dim3(512), dim3(256), 0, stream>>>(
            x, vis, dets, inds, kpA, kpB, Wqkv, bqkv, Wo, bo,
            W1, b1, W2, b2, g2, be2, g3, be3, out);
    } else {
        copy_x<<<dim3(2048), dim3(256), 0, stream>>>(
            (const f4v*)x, (f4v*)out, N4);
        er_fused_fb<<<dim3(NDB), dim3(256), 0, stream>>>(
            x, vis, dets, inds, Wqkv, bqkv, Wo, bo, W1, b1, W2, b2,
            g2, be2, g3, be3, out);
    }
}